// Round 2
// baseline (11667.224 us; speedup 1.0000x reference)
//
#include <hip/hip_runtime.h>

#define TT 2048
#define NH 15

#if __has_builtin(__builtin_amdgcn_exp2f)
#define EXP2(x) __builtin_amdgcn_exp2f(x)
#else
#define EXP2(x) exp2f(x)
#endif
#if __has_builtin(__builtin_amdgcn_rcpf)
#define RCP(x) __builtin_amdgcn_rcpf(x)
#else
#define RCP(x) (1.0f / (x))
#endif

__device__ __forceinline__ float sigm(float x) {
    // 1/(1+exp(-x)) = 1/(1+2^(-x*log2 e))
    return RCP(1.0f + EXP2(x * -1.4426950408889634f));
}
__device__ __forceinline__ float tanh_fast(float x) {
    // tanh(x) = 1 - 2/(exp(2x)+1)
    return fmaf(-2.0f, RCP(1.0f + EXP2(x * 2.8853900817779268f)), 1.0f);
}
__device__ __forceinline__ float shfl32(float v, int s) { return __shfl(v, s, 32); }

// Layout: 32 lanes per batch element (30 active). lane = half*15 + u.
//   half 0: owns gate rows i (u) and g (30+u)   -> zA=i, zB=g
//   half 1: owns gate rows f (15+u) and o (45+u)-> zA=f, zB=o
// Per-lane weights: 2 rows x 15 cols x 5 matrices = 150 fp32 (vs 300 in the
// 16-lane layout that spilled at VGPR=256). h/c state lives on half-1 lanes.
__global__ __launch_bounds__(256, 2)
void lstm3_kernel(const float* __restrict__ input,
                  const float* __restrict__ w_ih1, const float* __restrict__ w_hh1,
                  const float* __restrict__ b_ih1, const float* __restrict__ b_hh1,
                  const float* __restrict__ w_ih2, const float* __restrict__ w_hh2,
                  const float* __restrict__ b_ih2, const float* __restrict__ b_hh2,
                  const float* __restrict__ w_ih3, const float* __restrict__ w_hh3,
                  const float* __restrict__ b_ih3, const float* __restrict__ b_hh3,
                  const float* __restrict__ w_lin, const float* __restrict__ b_lin,
                  float* __restrict__ out)
{
    const int tid  = blockIdx.x * blockDim.x + threadIdx.x;
    const int lane = threadIdx.x & 31;
    const int elem = tid >> 5;
    const int u    = lane % 15;      // unit index 0..14 (lanes 30,31 alias 0,1 harmlessly)
    const int half = lane / 15;      // 0,1 active; 2 = pad lanes
    const bool on  = (half < 2);

    const int rA = half * NH + u;    // gate row for zA (i or f)
    const int rB = rA + 2 * NH;      // gate row for zB (g or o)

    // ---- lane-private weights (registers) ----
    float wA1[NH], wB1[NH];                      // w_hh1 rows
    float wA2i[NH], wA2h[NH], wB2i[NH], wB2h[NH];
    float wA3i[NH], wA3h[NH], wB3i[NH], wB3h[NH];
    const int sA = on ? rA * NH : 0;
    const int sB = on ? rB * NH : 0;
#pragma unroll
    for (int c = 0; c < NH; ++c) {
        wA1[c]  = on ? w_hh1[sA + c] : 0.f;
        wB1[c]  = on ? w_hh1[sB + c] : 0.f;
        wA2i[c] = on ? w_ih2[sA + c] : 0.f;
        wA2h[c] = on ? w_hh2[sA + c] : 0.f;
        wB2i[c] = on ? w_ih2[sB + c] : 0.f;
        wB2h[c] = on ? w_hh2[sB + c] : 0.f;
        wA3i[c] = on ? w_ih3[sA + c] : 0.f;
        wA3h[c] = on ? w_hh3[sA + c] : 0.f;
        wB3i[c] = on ? w_ih3[sB + c] : 0.f;
        wB3h[c] = on ? w_hh3[sB + c] : 0.f;
    }
    const float wiA = on ? w_ih1[rA] : 0.f;
    const float wiB = on ? w_ih1[rB] : 0.f;
    const float bA1 = on ? (b_ih1[rA] + b_hh1[rA]) : 0.f;
    const float bB1 = on ? (b_ih1[rB] + b_hh1[rB]) : 0.f;
    const float bA2 = on ? (b_ih2[rA] + b_hh2[rA]) : 0.f;
    const float bB2 = on ? (b_ih2[rB] + b_hh2[rB]) : 0.f;
    const float bA3 = on ? (b_ih3[rA] + b_hh3[rA]) : 0.f;
    const float bB3 = on ? (b_ih3[rB] + b_hh3[rB]) : 0.f;
    // actB: half0 -> tanh(z) = 2*sigm(2z)-1 ; half1 -> sigm(z). Wave-uniform via lane consts.
    const float kScl = (half == 0) ? 2.f : 1.f;
    const float kMul = (half == 0) ? 2.f : 1.f;
    const float kAdd = (half == 0) ? -1.f : 0.f;
    const float wlv  = (half == 1) ? w_lin[u] : 0.f;
    const float blv  = b_lin[0];

    // ---- state (valid on half-1 lanes) ----
    float h1 = 0.f, c1 = 0.f, h2 = 0.f, c2 = 0.f, h3 = 0.f, c3 = 0.f;

    const float* xp = input + (size_t)elem * TT;
    float* op = out + (size_t)elem * TT;

    for (int t0 = 0; t0 < TT; t0 += 32) {
        float xt = xp[t0 + lane];   // coalesced 32-step input tile
        float ysel = 0.f;
#pragma unroll 1
        for (int tt = 0; tt < 32; ++tt) {
            const float x = shfl32(xt, tt);

            // ---------------- cell 1 ----------------
            float zA = fmaf(wiA, x, bA1);
            float zB = fmaf(wiB, x, bB1);
#pragma unroll
            for (int c = 0; c < NH; ++c) {
                const float hb = shfl32(h1, NH + c);
                zA = fmaf(wA1[c], hb, zA);
                zB = fmaf(wB1[c], hb, zB);
            }
            {
                float aA = sigm(zA);                          // i (h0) / f (h1)
                float aB = fmaf(kMul, sigm(kScl * zB), kAdd); // g (h0) / o (h1)
                float p  = aA * aB;                           // i*g on half0
                float pv = shfl32(p, u);
                c1 = fmaf(aA, c1, pv);                        // f*c + i*g (half1)
                h1 = aB * tanh_fast(c1);                      // o*tanh(c) (half1)
            }

            // ---------------- cell 2 ----------------
            zA = bA2; zB = bB2;
#pragma unroll
            for (int c = 0; c < NH; ++c) {
                const float hb = shfl32(h1, NH + c);
                const float gb = shfl32(h2, NH + c);
                zA = fmaf(wA2i[c], hb, fmaf(wA2h[c], gb, zA));
                zB = fmaf(wB2i[c], hb, fmaf(wB2h[c], gb, zB));
            }
            {
                float aA = sigm(zA);
                float aB = fmaf(kMul, sigm(kScl * zB), kAdd);
                float p  = aA * aB;
                float pv = shfl32(p, u);
                c2 = fmaf(aA, c2, pv);
                h2 = aB * tanh_fast(c2);
            }

            // ---------------- cell 3 ----------------
            zA = bA3; zB = bB3;
#pragma unroll
            for (int c = 0; c < NH; ++c) {
                const float hb = shfl32(h2, NH + c);
                const float gb = shfl32(h3, NH + c);
                zA = fmaf(wA3i[c], hb, fmaf(wA3h[c], gb, zA));
                zB = fmaf(wB3i[c], hb, fmaf(wB3h[c], gb, zB));
            }
            {
                float aA = sigm(zA);
                float aB = fmaf(kMul, sigm(kScl * zB), kAdd);
                float p  = aA * aB;
                float pv = shfl32(p, u);
                c3 = fmaf(aA, c3, pv);
                h3 = aB * tanh_fast(c3);
            }

            // ---------------- linear head ----------------
            float q = wlv * h3;          // nonzero only on half-1 lanes
#pragma unroll
            for (int m = 1; m < 32; m <<= 1) q += __shfl_xor(q, m, 32);
            const float yv = q + blv;
            ysel = (tt == lane) ? yv : ysel;  // lane k keeps step t0+k
        }
        op[t0 + lane] = ysel;            // coalesced 32-step output tile
    }
}

extern "C" void kernel_launch(void* const* d_in, const int* in_sizes, int n_in,
                              void* d_out, int out_size, void* d_ws, size_t ws_size,
                              hipStream_t stream) {
    const float* input = (const float*)d_in[0];
    const float* w_ih1 = (const float*)d_in[1];
    const float* w_hh1 = (const float*)d_in[2];
    const float* b_ih1 = (const float*)d_in[3];
    const float* b_hh1 = (const float*)d_in[4];
    const float* w_ih2 = (const float*)d_in[5];
    const float* w_hh2 = (const float*)d_in[6];
    const float* b_ih2 = (const float*)d_in[7];
    const float* b_hh2 = (const float*)d_in[8];
    const float* w_ih3 = (const float*)d_in[9];
    const float* w_hh3 = (const float*)d_in[10];
    const float* b_ih3 = (const float*)d_in[11];
    const float* b_hh3 = (const float*)d_in[12];
    const float* w_lin = (const float*)d_in[13];
    const float* b_lin = (const float*)d_in[14];
    float* out = (float*)d_out;

    const int B = in_sizes[0] / TT;              // 8192
    const int threads = 256;
    const int blocks = (B * 32) / threads;       // 1024

    lstm3_kernel<<<blocks, threads, 0, stream>>>(
        input, w_ih1, w_hh1, b_ih1, b_hh1,
        w_ih2, w_hh2, b_ih2, b_hh2,
        w_ih3, w_hh3, b_ih3, b_hh3,
        w_lin, b_lin, out);
}